// Round 8
// baseline (8732.088 us; speedup 1.0000x reference)
//
#include <hip/hip_runtime.h>

typedef unsigned short u16;
typedef unsigned int u32;
typedef unsigned long long u64;
typedef __attribute__((ext_vector_type(8))) short short8;
typedef __attribute__((ext_vector_type(4))) float floatx4;
typedef __attribute__((ext_vector_type(4))) u32 u32x4;

#define B_   256
#define T_   512
#define E_   512
#define H_   1024
#define G4H  4096
#define KCAT 1536
#define M_   1024

__device__ __forceinline__ u16 f2bf(float f) {
    union { float f; unsigned u; } v; v.f = f;
    unsigned r = (v.u + 0x7fffu + ((v.u >> 16) & 1u)) >> 16;
    return (u16)r;
}
__device__ __forceinline__ float sigf(float x) {
    return __fdividef(1.0f, 1.0f + __expf(-x));
}
__device__ __forceinline__ float tanh_f(float x) {
    return 1.0f - __fdividef(2.0f, __expf(2.0f * x) + 1.0f);
}
// device-coherent 16B load (bypass L1/L2 -> always fresh at MALL), BYTE imm
__device__ __forceinline__ u32x4 load_sc(const u16* p, int imm) {
    u32x4 r;
    asm volatile("global_load_dwordx4 %0, %1, off offset:%2 sc0 sc1"
                 : "=v"(r) : "v"(p), "i"(imm) : "memory");
    return r;
}
// plain cached 16B load via asm (manual vmcnt accounting stays exact)
__device__ __forceinline__ u32x4 load_g(const u16* p, int imm) {
    u32x4 r;
    asm volatile("global_load_dwordx4 %0, %1, off offset:%2"
                 : "=v"(r) : "v"(p), "i"(imm) : "memory");
    return r;
}
__device__ __forceinline__ short8 as_s8(u32x4 v) {
    union { u32x4 u; short8 s; } x; x.u = v; return x.s;
}

// ---------------- prep kernels ----------------

// rank rows by x_index descending (stable): perm[rank]=orig, sxi[rank]=xi
__global__ void sort_rows(const int* __restrict__ x_index,
                          int* __restrict__ perm, int* __restrict__ sxi) {
    __shared__ int xl[B_];
    int tid = threadIdx.x;
    xl[tid] = x_index[tid];
    __syncthreads();
    int mine = xl[tid], rank = 0;
    for (int j = 0; j < B_; ++j)
        rank += (xl[j] > mine) || (xl[j] == mine && j < tid);
    perm[rank] = tid;
    sxi[rank] = mine;
}

// emb_bf[srow][t][e] = bf16(tab[x[perm[srow]][t]][e])
__global__ void prep_emb(const int* __restrict__ x, const float* __restrict__ tab,
                         const int* __restrict__ perm, u16* __restrict__ emb) {
    int idx = (blockIdx.x * 256 + threadIdx.x) * 4;   // [0, B*T*E)
    int srow = idx >> 18;                             // / (T*E)
    int t    = (idx >> 9) & 511;
    int e    = idx & 511;
    int orig = perm[srow];
    int xv   = x[orig * T_ + t];
    float4 v = *(const float4*)(tab + (size_t)xv * E_ + e);
    ushort4 o; o.x = f2bf(v.x); o.y = f2bf(v.y); o.z = f2bf(v.z); o.w = f2bf(v.w);
    *(ushort4*)(emb + idx) = o;
}

__global__ void prep_wcat(const float* __restrict__ Whh, const float* __restrict__ Wih,
                          u16* __restrict__ wcat) {
    int idx = (blockIdx.x * 256 + threadIdx.x) * 4;   // [0, 4096*1536)
    int g = idx / KCAT;
    int k = idx - g * KCAT;
    const float* src = (k < H_) ? (Whh + (size_t)g * H_ + k)
                                : (Wih + (size_t)g * E_ + (k - H_));
    float4 v = *(const float4*)src;
    ushort4 o; o.x = f2bf(v.x); o.y = f2bf(v.y); o.z = f2bf(v.z); o.w = f2bf(v.w);
    *(ushort4*)(wcat + idx) = o;
}

__global__ void prep_fc1w(const float* __restrict__ src, u16* __restrict__ dst) {
    int idx = (blockIdx.x * 256 + threadIdx.x) * 4;
    float4 v = *(const float4*)(src + idx);
    ushort4 o; o.x = f2bf(v.x); o.y = f2bf(v.y); o.z = f2bf(v.z); o.w = f2bf(v.w);
    *(ushort4*)(dst + idx) = o;
}

__global__ void prep_bias(const float* __restrict__ bih, const float* __restrict__ bhh,
                          float* __restrict__ bias) {
    int i = blockIdx.x * 256 + threadIdx.x;
    bias[i] = bih[i] + bhh[i];
}

// sorted h0 (bf16) and c0 (f32)
__global__ void prep_state(const float* __restrict__ h0, const float* __restrict__ c0,
                           const int* __restrict__ perm,
                           u16* __restrict__ hbuf0, float* __restrict__ c0p) {
    int i = blockIdx.x * 256 + threadIdx.x;           // [0, B*H)
    int srow = i >> 10, col = i & 1023;
    int orig = perm[srow];
    hbuf0[i] = f2bf(h0[(size_t)orig * H_ + col]);
    c0p[i]   = c0[(size_t)orig * H_ + col];
}

__global__ void zero_flags(u32* __restrict__ f) {
    f[blockIdx.x * 256 + threadIdx.x] = 0;            // [0, 16*128)
}

// ---------------- persistent LSTM ----------------
// 256 blocks x 512 threads, 1 block/CU. grp = bid>>7 owns sorted rows
// [grp*128, grp*128+128); cb = bid&127 owns h-cols [8cb, 8cb+8) (32 gate-cols).
// Wave w owns 16-row tile w: MFMA A-fragments DIRECTLY from global (no LDS
// staging), fully manual merged pipeline:
//   poll(t) -> issue 16 emb loads (cached asm) -> issue 16 h loads (sc0sc1)
//   -> 8 emb-MFMA chunks, vmcnt(30-2c)  [h MALL latency hides under these]
//   -> 16 h-MFMA chunks, vmcnt(14 / 30-2c) with rolling re-issue.
// FIFO accounting: emb = pos 1..16, h = pos 17..32, re-issues append; all
// constants derived from "wait until target position complete".
// Poll sits BEFORE any loads so no asm load is in flight across the
// compiler-tracked atomic (round-2 poison). sched_barrier(0) after each
// manual waitcnt prevents MFMA hoisting past the wait (guide rule #18).
// Sync = round-0-verified protocol: per-(grp,tile,cb) monotonic u32 flags.

__global__ __launch_bounds__(512, 2) void lstm_persist(
    const u16* __restrict__ emb, const u16* __restrict__ wcat,
    const float* __restrict__ bias, const float* __restrict__ c0p,
    const int* __restrict__ sxi,
    u16* __restrict__ hbuf, float* __restrict__ hn, u32* __restrict__ flags)
{
    __shared__ __align__(16) u16 Wl[32 * 1544];       // 98,816 B  weights
    __shared__ __align__(16) float Gf_all[8][640];    // 20,480 B  epilogue scratch

    const int tid  = threadIdx.x;
    const int w    = tid >> 6;
    const int lane = tid & 63;
    const int lr   = lane & 15;
    const int lk   = lane >> 4;
    const int grp  = blockIdx.x >> 7;
    const int cb   = blockIdx.x & 127;
    const int erow = lane >> 2;
    const int e2   = (lane & 3) * 2;
    const int rowg = grp * 128 + w * 16 + erow;       // epilogue/store (4 lanes/row)
    const int rowf = grp * 128 + w * 16 + lr;         // fragment loads (1 lane/row)

    // ---- one-time: weights -> LDS (rows: [i x8 | f x8 | g x8 | o x8]) ----
    for (int i = tid; i < 32 * 192; i += 512) {
        int r = i / 192, kq = i - r * 192;
        int gcol = (r >> 3) * H_ + cb * 8 + (r & 7);
        *(u32x4*)&Wl[r * 1544 + kq * 8] =
            *(const u32x4*)(wcat + (size_t)gcol * KCAT + kq * 8);
    }
    __syncthreads();   // the ONLY block barrier

    const int tmax_w   = sxi[grp * 128 + w * 16];
    const int xi_lane  = sxi[rowg];
    float2 cc = *(const float2*)(c0p + (size_t)rowg * H_ + cb * 8 + e2);
    const float2 bI = *(const float2*)(bias + 0 * H_ + cb * 8 + e2);
    const float2 bF = *(const float2*)(bias + 1 * H_ + cb * 8 + e2);
    const float2 bG = *(const float2*)(bias + 2 * H_ + cb * 8 + e2);
    const float2 bO = *(const float2*)(bias + 3 * H_ + cb * 8 + e2);

    floatx4 acc0, acc1;
    // A-frags va0 (k kk..kk+32) and va1 (kk+32..kk+64) straight into MFMA.
    auto MFMA4 = [&](u32x4 va0, u32x4 va1, int kk) {
        short8 a0 = as_s8(va0), a1 = as_s8(va1);
        short8 b00 = *(const short8*)&Wl[lr * 1544 + kk + lk * 8];
        short8 b01 = *(const short8*)&Wl[(16 + lr) * 1544 + kk + lk * 8];
        acc0 = __builtin_amdgcn_mfma_f32_16x16x32_bf16(a0, b00, acc0, 0, 0, 0);
        acc1 = __builtin_amdgcn_mfma_f32_16x16x32_bf16(a0, b01, acc1, 0, 0, 0);
        short8 b10 = *(const short8*)&Wl[lr * 1544 + kk + 32 + lk * 8];
        short8 b11 = *(const short8*)&Wl[(16 + lr) * 1544 + kk + 32 + lk * 8];
        acc0 = __builtin_amdgcn_mfma_f32_16x16x32_bf16(a1, b10, acc0, 0, 0, 0);
        acc1 = __builtin_amdgcn_mfma_f32_16x16x32_bf16(a1, b11, acc1, 0, 0, 0);
    };

    for (int t = 0; t <= tmax_w; ++t) {
        const u16* hread  = hbuf + (size_t)(t & 1) * (B_ * H_);
        u16*       hwrite = hbuf + (size_t)((t + 1) & 1) * (B_ * H_);
        acc0 = (floatx4){0.f, 0.f, 0.f, 0.f};
        acc1 = (floatx4){0.f, 0.f, 0.f, 0.f};

        // ---- wait for h_t FIRST (no loads in flight across the poll) ----
        if (t > 0) {
            u64* fp = (u64*)(flags + (grp * 8 + w) * 128);
            while (true) {
                u64 v = __hip_atomic_load(&fp[lane], __ATOMIC_RELAXED,
                                          __HIP_MEMORY_SCOPE_AGENT);
                if (__all(((u32)v >= (u32)t) && ((u32)(v >> 32) >= (u32)t))) break;
                __builtin_amdgcn_s_sleep(1);
            }
        }

        // ---- issue 16 emb loads (pos 1..16), then 16 h loads (pos 17..32) ----
        const u16* ebase = emb + ((size_t)rowf * T_ + t) * E_ + lk * 8;
        u32x4 ev[8][2];
        #pragma unroll
        for (int c = 0; c < 8; ++c) {
            ev[c][0] = load_g(ebase, c * 128);
            ev[c][1] = load_g(ebase, c * 128 + 64);
        }
        const u16* hbase = hread + (size_t)rowf * H_ + lk * 8;
        u32x4 hv[8][2];
        #pragma unroll
        for (int c = 0; c < 8; ++c) {
            hv[c][0] = load_sc(hbase, c * 128);
            hv[c][1] = load_sc(hbase, c * 128 + 64);
        }

        // ---- emb MFMAs (k 1024..1535) while h loads are in flight ----
        #pragma unroll
        for (int c = 0; c < 8; ++c) {
            asm volatile("s_waitcnt vmcnt(%0)" :: "i"(30 - 2 * c) : "memory");
            __builtin_amdgcn_sched_barrier(0);
            MFMA4(ev[c][0], ev[c][1], 1024 + c * 64);
        }

        // ---- h MFMAs (k 0..1023), rolling re-issue, 16 h in flight ----
        #pragma unroll
        for (int c = 0; c < 16; ++c) {
            const int pend = (c < 8) ? 14 : (30 - 2 * c);
            asm volatile("s_waitcnt vmcnt(%0)" :: "i"(pend) : "memory");
            __builtin_amdgcn_sched_barrier(0);
            u32x4 va0 = hv[c & 7][0], va1 = hv[c & 7][1];
            if (c < 8) {
                hv[c][0] = load_sc(hbase, (c + 8) * 128);
                hv[c][1] = load_sc(hbase, (c + 8) * 128 + 64);
            }
            MFMA4(va0, va1, c * 64);
        }

        // ---- epilogue: wave-internal LDS transpose ----
        float* Gf = Gf_all[w];                        // [4 gates][16 rows][10]
        #pragma unroll
        for (int ct = 0; ct < 2; ++ct) {
            const floatx4 aa = ct ? acc1 : acc0;
            const int gate = ct * 2 + (lr >> 3);
            const int hc   = lr & 7;
            #pragma unroll
            for (int r = 0; r < 4; ++r)
                Gf[(gate * 16 + lk * 4 + r) * 10 + hc] = aa[r];
        }
        float2 g_i = *(float2*)&Gf[(0 * 16 + erow) * 10 + e2];
        float2 g_f = *(float2*)&Gf[(1 * 16 + erow) * 10 + e2];
        float2 g_g = *(float2*)&Gf[(2 * 16 + erow) * 10 + e2];
        float2 g_o = *(float2*)&Gf[(3 * 16 + erow) * 10 + e2];

        float i0 = sigf(g_i.x + bI.x), i1 = sigf(g_i.y + bI.y);
        float f0 = sigf(g_f.x + bF.x), f1 = sigf(g_f.y + bF.y);
        float q0 = tanh_f(g_g.x + bG.x), q1 = tanh_f(g_g.y + bG.y);
        float o0 = sigf(g_o.x + bO.x), o1 = sigf(g_o.y + bO.y);
        cc.x = f0 * cc.x + i0 * q0;
        cc.y = f1 * cc.y + i1 * q1;
        float h0f = o0 * tanh_f(cc.x);
        float h1f = o1 * tanh_f(cc.y);

        u32 packed = (u32)f2bf(h0f) | ((u32)f2bf(h1f) << 16);
        __hip_atomic_store((u32*)(hwrite + (size_t)rowg * H_ + cb * 8 + e2),
                           packed, __ATOMIC_RELAXED, __HIP_MEMORY_SCOPE_AGENT);
        if (xi_lane == t)
            *(float2*)(hn + (size_t)rowg * H_ + cb * 8 + e2) = make_float2(h0f, h1f);
        asm volatile("s_waitcnt vmcnt(0)" ::: "memory");
        if (lane == 0)
            __hip_atomic_store(flags + (grp * 8 + w) * 128 + cb, (u32)(t + 1),
                               __ATOMIC_RELAXED, __HIP_MEMORY_SCOPE_AGENT);
    }
}

// ---------------- tail ----------------

__global__ void hn_convert(const float* __restrict__ hn, u16* __restrict__ hnbf) {
    int i = blockIdx.x * 256 + threadIdx.x;
    hnbf[i] = f2bf(hn[i]);
}

__global__ __launch_bounds__(256) void fc1_kernel(
    const u16* __restrict__ A, const u16* __restrict__ Bw,
    const float* __restrict__ bvec, float* __restrict__ z)
{
    __shared__ __align__(16) u16 Als[64 * 72];
    __shared__ __align__(16) u16 Bls[64 * 72];
    const int tid = threadIdx.x;
    const int rowbase = blockIdx.y * 64;
    const int colbase = blockIdx.x * 64;
    floatx4 acc[4] = {{0,0,0,0},{0,0,0,0},{0,0,0,0},{0,0,0,0}};
    const int w = tid >> 6, lane = tid & 63, lr = lane & 15, lk = lane >> 4;

    for (int s = 0; s < H_ / 64; ++s) {
        int k0 = s * 64;
        #pragma unroll
        for (int cc2 = 0; cc2 < 2; ++cc2) {
            int c = tid + cc2 * 256;
            int row = c >> 3, kg = c & 7, kglob = k0 + kg * 8;
            *(u32x4*)&Als[(row * 9 + kg) * 8] =
                *(const u32x4*)(A + (size_t)(rowbase + row) * H_ + kglob);
            *(u32x4*)&Bls[(row * 9 + kg) * 8] =
                *(const u32x4*)(Bw + (size_t)(colbase + row) * H_ + kglob);
        }
        __syncthreads();
        #pragma unroll
        for (int ks = 0; ks < 2; ++ks) {
            short8 a = *(const short8*)&Als[((16 * w + lr) * 9 + ks * 4 + lk) * 8];
            #pragma unroll
            for (int q = 0; q < 4; ++q) {
                short8 b = *(const short8*)&Bls[((q * 16 + lr) * 9 + ks * 4 + lk) * 8];
                acc[q] = __builtin_amdgcn_mfma_f32_16x16x32_bf16(a, b, acc[q], 0, 0, 0);
            }
        }
        __syncthreads();
    }
    #pragma unroll
    for (int q = 0; q < 4; ++q) {
        int col = colbase + q * 16 + lr;
        float bb = bvec[col];
        #pragma unroll
        for (int r = 0; r < 4; ++r) {
            int row = rowbase + 16 * w + lk * 4 + r;
            z[(size_t)row * M_ + col] = tanh_f(acc[q][r] + bb);
        }
    }
}

__global__ __launch_bounds__(64) void fc2_softmax(
    const float* __restrict__ z, const float* __restrict__ wmat,
    const float* __restrict__ bvec, const int* __restrict__ perm,
    float* __restrict__ out)
{
    int bi = blockIdx.x;
    int lane = threadIdx.x;
    const float4* zr = (const float4*)(z + (size_t)bi * M_);
    const float4* w0 = (const float4*)(wmat);
    const float4* w1 = (const float4*)(wmat + M_);
    float s0 = 0.f, s1 = 0.f;
    for (int k = lane; k < M_ / 4; k += 64) {
        float4 zv = zr[k]; float4 a = w0[k]; float4 c = w1[k];
        s0 += zv.x * a.x + zv.y * a.y + zv.z * a.z + zv.w * a.w;
        s1 += zv.x * c.x + zv.y * c.y + zv.z * c.z + zv.w * c.w;
    }
    for (int off = 32; off; off >>= 1) {
        s0 += __shfl_down(s0, off);
        s1 += __shfl_down(s1, off);
    }
    if (lane == 0) {
        float l0 = s0 + bvec[0], l1 = s1 + bvec[1];
        float m = fmaxf(l0, l1);
        float lse = m + __logf(__expf(l0 - m) + __expf(l1 - m));
        int orig = perm[bi];
        out[orig * 2 + 0] = l0 - lse;
        out[orig * 2 + 1] = l1 - lse;
    }
}

// ---------------- launch ----------------

extern "C" void kernel_launch(void* const* d_in, const int* in_sizes, int n_in,
                              void* d_out, int out_size, void* d_ws, size_t ws_size,
                              hipStream_t stream)
{
    const int*   x       = (const int*)  d_in[0];
    const int*   x_index = (const int*)  d_in[1];
    const float* emb_t   = (const float*)d_in[2];
    const float* W_ih    = (const float*)d_in[3];
    const float* W_hh    = (const float*)d_in[4];
    const float* b_ih    = (const float*)d_in[5];
    const float* b_hh    = (const float*)d_in[6];
    const float* fc1_w   = (const float*)d_in[7];
    const float* fc1_b   = (const float*)d_in[8];
    const float* fc2_w   = (const float*)d_in[9];
    const float* fc2_b   = (const float*)d_in[10];
    const float* h0      = (const float*)d_in[11];
    const float* c0      = (const float*)d_in[12];
    float* out = (float*)d_out;

    char* p = (char*)d_ws;
    u16*   emb_bf = (u16*)p;   p += (size_t)B_ * T_ * E_ * 2;   // 134 MB
    u16*   wcat   = (u16*)p;   p += (size_t)G4H * KCAT * 2;     // 12.6 MB
    u16*   fc1wbf = (u16*)p;   p += (size_t)M_ * H_ * 2;        // 2 MB
    float* bias   = (float*)p; p += (size_t)G4H * 4;
    u16*   hbuf   = (u16*)p;   p += (size_t)2 * B_ * H_ * 2;    // ping-pong h
    float* c0p    = (float*)p; p += (size_t)B_ * H_ * 4;
    float* hn     = (float*)p; p += (size_t)B_ * H_ * 4;
    u16*   hnbf   = (u16*)p;   p += (size_t)B_ * H_ * 2;
    float* zbuf   = (float*)p; p += (size_t)B_ * M_ * 4;
    int*   perm   = (int*)p;   p += (size_t)B_ * 4;
    int*   sxi    = (int*)p;   p += (size_t)B_ * 4;
    u32*   flags  = (u32*)p;   p += (size_t)16 * 128 * 4;

    sort_rows <<<1,     256, 0, stream>>>(x_index, perm, sxi);
    prep_emb  <<<65536, 256, 0, stream>>>(x, emb_t, perm, emb_bf);
    prep_wcat <<<6144,  256, 0, stream>>>(W_hh, W_ih, wcat);
    prep_fc1w <<<1024,  256, 0, stream>>>(fc1_w, fc1wbf);
    prep_bias <<<16,    256, 0, stream>>>(b_ih, b_hh, bias);
    prep_state<<<1024,  256, 0, stream>>>(h0, c0, perm, hbuf, c0p);
    zero_flags<<<8,     256, 0, stream>>>(flags);

    lstm_persist<<<256, 512, 0, stream>>>(emb_bf, wcat, bias, c0p, sxi,
                                          hbuf, hn, flags);

    hn_convert <<<1024, 256, 0, stream>>>(hn, hnbf);
    fc1_kernel <<<dim3(16, 4), 256, 0, stream>>>(hnbf, fc1wbf, fc1_b, zbuf);
    fc2_softmax<<<256, 64, 0, stream>>>(zbuf, fc2_w, fc2_b, perm, out);
}

// Round 9
// 3615.422 us; speedup vs baseline: 2.4152x; 2.4152x over previous
//
#include <hip/hip_runtime.h>

typedef unsigned short u16;
typedef unsigned int u32;
typedef unsigned long long u64;
typedef __attribute__((ext_vector_type(8))) short short8;
typedef __attribute__((ext_vector_type(4))) float floatx4;
typedef __attribute__((ext_vector_type(4))) u32 u32x4;

#define B_   256
#define T_   512
#define E_   512
#define H_   1024
#define G4H  4096
#define KCAT 1536
#define M_   1024

// lstm_persist geometry
#define RG_N    8        // row groups
#define RG_ROWS 32       // rows per group
#define CB_N    32       // col blocks (32 h-cols each)
#define HC_B    32       // h-cols per block
#define NW      8        // waves per block
#define AL_STRIDE 1544   // u16 per A-row in LDS (1536 + 8 pad, rows 16B-aligned)

__device__ __forceinline__ u16 f2bf(float f) {
    union { float f; unsigned u; } v; v.f = f;
    unsigned r = (v.u + 0x7fffu + ((v.u >> 16) & 1u)) >> 16;
    return (u16)r;
}
__device__ __forceinline__ float sigf(float x) {
    return __fdividef(1.0f, 1.0f + __expf(-x));
}
__device__ __forceinline__ float tanh_f(float x) {
    return 1.0f - __fdividef(2.0f, __expf(2.0f * x) + 1.0f);
}

// ---------------- prep kernels ----------------

// rank rows by x_index descending (stable): perm[rank]=orig, sxi[rank]=xi
__global__ void sort_rows(const int* __restrict__ x_index,
                          int* __restrict__ perm, int* __restrict__ sxi) {
    __shared__ int xl[B_];
    int tid = threadIdx.x;
    xl[tid] = x_index[tid];
    __syncthreads();
    int mine = xl[tid], rank = 0;
    for (int j = 0; j < B_; ++j)
        rank += (xl[j] > mine) || (xl[j] == mine && j < tid);
    perm[rank] = tid;
    sxi[rank] = mine;
}

// emb_bf[srow][t][e] = bf16(tab[x[perm[srow]][t]][e])
__global__ void prep_emb(const int* __restrict__ x, const float* __restrict__ tab,
                         const int* __restrict__ perm, u16* __restrict__ emb) {
    int idx = (blockIdx.x * 256 + threadIdx.x) * 4;   // [0, B*T*E)
    int srow = idx >> 18;                             // / (T*E)
    int t    = (idx >> 9) & 511;
    int e    = idx & 511;
    int orig = perm[srow];
    int xv   = x[orig * T_ + t];
    float4 v = *(const float4*)(tab + (size_t)xv * E_ + e);
    ushort4 o; o.x = f2bf(v.x); o.y = f2bf(v.y); o.z = f2bf(v.z); o.w = f2bf(v.w);
    *(ushort4*)(emb + idx) = o;
}

__global__ void prep_wcat(const float* __restrict__ Whh, const float* __restrict__ Wih,
                          u16* __restrict__ wcat) {
    int idx = (blockIdx.x * 256 + threadIdx.x) * 4;   // [0, 4096*1536)
    int g = idx / KCAT;
    int k = idx - g * KCAT;
    const float* src = (k < H_) ? (Whh + (size_t)g * H_ + k)
                                : (Wih + (size_t)g * E_ + (k - H_));
    float4 v = *(const float4*)src;
    ushort4 o; o.x = f2bf(v.x); o.y = f2bf(v.y); o.z = f2bf(v.z); o.w = f2bf(v.w);
    *(ushort4*)(wcat + idx) = o;
}

__global__ void prep_fc1w(const float* __restrict__ src, u16* __restrict__ dst) {
    int idx = (blockIdx.x * 256 + threadIdx.x) * 4;
    float4 v = *(const float4*)(src + idx);
    ushort4 o; o.x = f2bf(v.x); o.y = f2bf(v.y); o.z = f2bf(v.z); o.w = f2bf(v.w);
    *(ushort4*)(dst + idx) = o;
}

__global__ void prep_bias(const float* __restrict__ bih, const float* __restrict__ bhh,
                          float* __restrict__ bias) {
    int i = blockIdx.x * 256 + threadIdx.x;
    bias[i] = bih[i] + bhh[i];
}

// sorted h0 (bf16) and c0 (f32)
__global__ void prep_state(const float* __restrict__ h0, const float* __restrict__ c0,
                           const int* __restrict__ perm,
                           u16* __restrict__ hbuf0, float* __restrict__ c0p) {
    int i = blockIdx.x * 256 + threadIdx.x;           // [0, B*H)
    int srow = i >> 10, col = i & 1023;
    int orig = perm[srow];
    hbuf0[i] = f2bf(h0[(size_t)orig * H_ + col]);
    c0p[i]   = c0[(size_t)orig * H_ + col];
}

__global__ void zero_flags(u32* __restrict__ f) {
    f[blockIdx.x * 256 + threadIdx.x] = 0;
}

// ---------------- persistent LSTM (register-resident weights) ----------------
// 256 blocks x 512 threads (8 waves), 1 block/CU.
//   rg = bid>>5 owns sorted rows [rg*32, rg*32+32)
//   cb = bid&31 owns h-cols [cb*32, cb*32+32) (=128 gate-cols)
// Each wave holds 16 gate-cols x K=1536 of W in 192 VGPRs (48 short8 B-frags).
// A (h||emb for the block's 32 rows) staged ONCE per block into LDS, shared by
// all 8 waves -> coherent h traffic = 64KB/block/step = 16 MB/step total
// (vs 64 MB/step in the 8-col structure -> 4x less MALL pressure).
// CONSERVATIVE implementation (after r4/r5/r8 failures of the overlapped
// variants): ZERO inline asm in the step loop. All cross-block data moves via
// compiler-tracked __hip_atomic_* (relaxed, agent). Simple barrier phases:
//   poll -> stage h+emb -> S1 -> 48 MFMA ks -> epilogue -> h-store ->
//   S2 (__syncthreads: compiler drains vmcnt before s_barrier) -> tid0 flag.
// Sync protocol (round-0-verified shape): monotonic u32 flag per block,
// 32 flags per row-group, consumer polls with 32 lanes.

__global__ __launch_bounds__(512, 2) void lstm_persist(
    const u16* __restrict__ emb, const u16* __restrict__ wcat,
    const float* __restrict__ bias, const float* __restrict__ c0p,
    const int* __restrict__ sxi,
    u16* __restrict__ hbuf, float* __restrict__ hn, u32* __restrict__ flags)
{
    __shared__ __align__(16) u16 Albuf[32 * AL_STRIDE];   // 98,816 B
    __shared__ __align__(16) float Gf_all[NW][640];       // 20,480 B

    const int tid  = threadIdx.x;
    const int w    = tid >> 6;
    const int lane = tid & 63;
    const int lr   = lane & 15;
    const int lk   = lane >> 4;
    const int rg   = blockIdx.x >> 5;
    const int cb   = blockIdx.x & 31;

    // ---- B fragments -> registers: wave w covers h-cols w*4..w*4+3 ----
    // output col n=lr maps to (gate = lr&3, hl = lr>>2); B[n][k] = W[gc(n)][k]
    const int gc = (lr & 3) * H_ + cb * HC_B + w * 4 + (lr >> 2);
    const u16* wrow = wcat + (size_t)gc * KCAT + lk * 8;
    short8 Breg[48];
    #pragma unroll
    for (int ks = 0; ks < 48; ++ks)
        Breg[ks] = *(const short8*)(wrow + ks * 32);

    // ---- per-lane output state: lane = r0*2 + hp (row r0 of 32, col-pair hp) ----
    const int r0    = lane >> 1;                    // 0..31
    const int hp    = lane & 1;                     // 0..1
    const int hcol0 = cb * HC_B + w * 4 + hp * 2;   // first of 2 adjacent h-cols
    const int rowg  = rg * RG_ROWS + r0;
    const int tmax  = sxi[rg * RG_ROWS];            // group max (sorted desc)
    const int xi    = sxi[rowg];
    float2 cc = *(const float2*)(c0p + (size_t)rowg * H_ + hcol0);
    const float2 bI = *(const float2*)(bias + 0 * H_ + hcol0);
    const float2 bF = *(const float2*)(bias + 1 * H_ + hcol0);
    const float2 bG = *(const float2*)(bias + 2 * H_ + hcol0);
    const float2 bO = *(const float2*)(bias + 3 * H_ + hcol0);

    const u32* fp = flags + rg * CB_N;              // 32 cohort flags

    // staging geometry: wave w stages rows [w*4, w*4+4)
    const size_t hrow_u16 = (size_t)(rg * RG_ROWS + w * 4) * H_;
    const int    erow_l   = w * 4 + (lane >> 4);                   // local row
    const u16*   erow_p   = emb + (size_t)(rg * RG_ROWS + erow_l) * T_ * E_;
    const int    echunk   = (lane & 15) * 8;                       // u16 offset

    for (int t = 0; t <= tmax; ++t) {
        const u16* hread  = hbuf + (size_t)(t & 1) * (B_ * H_);
        u16*       hwrite = hbuf + (size_t)((t + 1) & 1) * (B_ * H_);

        // ---- wait for h_t (32 producer blocks of this row-group) ----
        if (t > 0) {
            while (true) {
                u32 v = (lane < 32)
                    ? __hip_atomic_load(fp + lane, __ATOMIC_RELAXED,
                                        __HIP_MEMORY_SCOPE_AGENT)
                    : (u32)t;
                if (__all((int)(v >= (u32)t))) break;
                __builtin_amdgcn_s_sleep(1);
            }
        }

        // ---- stage h(t): 8KB/wave via coherent atomic u64 loads ----
        {
            u64* hsrc = (u64*)(hread + hrow_u16);
            #pragma unroll
            for (int b = 0; b < 2; ++b) {
                u64 htmp[8];
                #pragma unroll
                for (int i = 0; i < 8; ++i)
                    htmp[i] = __hip_atomic_load(hsrc + (b * 8 + i) * 64 + lane,
                                                __ATOMIC_RELAXED,
                                                __HIP_MEMORY_SCOPE_AGENT);
                #pragma unroll
                for (int i = 0; i < 8; ++i) {
                    int hb = (b * 8 + i) * 512 + lane * 8;   // byte in 8KB slab
                    *(u64*)&Albuf[(w * 4 + (hb >> 11)) * AL_STRIDE + ((hb & 2047) >> 1)] = htmp[i];
                }
            }
        }
        // ---- stage emb(t): 4KB/wave, plain cached loads ----
        {
            const u16* esrc = erow_p + (size_t)t * E_ + echunk;
            u32x4 etmp[4];
            #pragma unroll
            for (int i = 0; i < 4; ++i)
                etmp[i] = *(const u32x4*)(esrc + i * 128);
            #pragma unroll
            for (int i = 0; i < 4; ++i)
                *(u32x4*)&Albuf[erow_l * AL_STRIDE + 1024 + echunk + i * 128] = etmp[i];
        }

        __syncthreads();   // S1: A fully staged (block-wide)

        // ---- 48 K-chunks: A from LDS, B from registers ----
        floatx4 acc00 = {0,0,0,0}, acc01 = {0,0,0,0};
        floatx4 acc10 = {0,0,0,0}, acc11 = {0,0,0,0};
        #pragma unroll
        for (int ks = 0; ks < 48; ++ks) {
            short8 a0 = *(const short8*)&Albuf[lr * AL_STRIDE + ks * 32 + lk * 8];
            short8 a1 = *(const short8*)&Albuf[(16 + lr) * AL_STRIDE + ks * 32 + lk * 8];
            if (ks & 1) {
                acc01 = __builtin_amdgcn_mfma_f32_16x16x32_bf16(a0, Breg[ks], acc01, 0, 0, 0);
                acc11 = __builtin_amdgcn_mfma_f32_16x16x32_bf16(a1, Breg[ks], acc11, 0, 0, 0);
            } else {
                acc00 = __builtin_amdgcn_mfma_f32_16x16x32_bf16(a0, Breg[ks], acc00, 0, 0, 0);
                acc10 = __builtin_amdgcn_mfma_f32_16x16x32_bf16(a1, Breg[ks], acc10, 0, 0, 0);
            }
        }

        // ---- epilogue: wave-private LDS transpose (Gf[32 rows][20]) ----
        float* Gf = Gf_all[w];
        #pragma unroll
        for (int r = 0; r < 4; ++r) {
            Gf[(lk * 4 + r) * 20 + lr]        = acc00[r] + acc01[r];
            Gf[(16 + lk * 4 + r) * 20 + lr]   = acc10[r] + acc11[r];
        }
        // lane reads 2 cols x 4 gates for its row r0
        float4 gA = *(float4*)&Gf[r0 * 20 + hp * 8];        // col hcol0:   i,f,g,o
        float4 gB = *(float4*)&Gf[r0 * 20 + hp * 8 + 4];    // col hcol0+1: i,f,g,o

        float i0 = sigf(gA.x + bI.x), f0 = sigf(gA.y + bF.x);
        float q0 = tanh_f(gA.z + bG.x), o0 = sigf(gA.w + bO.x);
        float i1 = sigf(gB.x + bI.y), f1 = sigf(gB.y + bF.y);
        float q1 = tanh_f(gB.z + bG.y), o1 = sigf(gB.w + bO.y);
        cc.x = f0 * cc.x + i0 * q0;
        cc.y = f1 * cc.y + i1 * q1;
        float h0f = o0 * tanh_f(cc.x);
        float h1f = o1 * tanh_f(cc.y);

        u32 packed = (u32)f2bf(h0f) | ((u32)f2bf(h1f) << 16);
        __hip_atomic_store((u32*)(hwrite + (size_t)rowg * H_ + hcol0), packed,
                           __ATOMIC_RELAXED, __HIP_MEMORY_SCOPE_AGENT);
        if (xi == t)
            *(float2*)(hn + (size_t)rowg * H_ + hcol0) = make_float2(h0f, h1f);

        // S2: __syncthreads — compiler drains vmcnt(0) before s_barrier, so all
        // waves' coherent h stores are at the MALL before tid0 raises the flag.
        __syncthreads();
        if (tid == 0)
            __hip_atomic_store(flags + rg * CB_N + cb, (u32)(t + 1),
                               __ATOMIC_RELAXED, __HIP_MEMORY_SCOPE_AGENT);
    }
}

// ---------------- tail ----------------

__global__ void hn_convert(const float* __restrict__ hn, u16* __restrict__ hnbf) {
    int i = blockIdx.x * 256 + threadIdx.x;
    hnbf[i] = f2bf(hn[i]);
}

__global__ __launch_bounds__(256) void fc1_kernel(
    const u16* __restrict__ A, const u16* __restrict__ Bw,
    const float* __restrict__ bvec, float* __restrict__ z)
{
    __shared__ __align__(16) u16 Als[64 * 72];
    __shared__ __align__(16) u16 Bls[64 * 72];
    const int tid = threadIdx.x;
    const int rowbase = blockIdx.y * 64;
    const int colbase = blockIdx.x * 64;
    floatx4 acc[4] = {{0,0,0,0},{0,0,0,0},{0,0,0,0},{0,0,0,0}};
    const int w = tid >> 6, lane = tid & 63, lr = lane & 15, lk = lane >> 4;

    for (int s = 0; s < H_ / 64; ++s) {
        int k0 = s * 64;
        #pragma unroll
        for (int cc2 = 0; cc2 < 2; ++cc2) {
            int c = tid + cc2 * 256;
            int row = c >> 3, kg = c & 7, kglob = k0 + kg * 8;
            *(u32x4*)&Als[(row * 9 + kg) * 8] =
                *(const u32x4*)(A + (size_t)(rowbase + row) * H_ + kglob);
            *(u32x4*)&Bls[(row * 9 + kg) * 8] =
                *(const u32x4*)(Bw + (size_t)(colbase + row) * H_ + kglob);
        }
        __syncthreads();
        #pragma unroll
        for (int ks = 0; ks < 2; ++ks) {
            short8 a = *(const short8*)&Als[((16 * w + lr) * 9 + ks * 4 + lk) * 8];
            #pragma unroll
            for (int q = 0; q < 4; ++q) {
                short8 b = *(const short8*)&Bls[((q * 16 + lr) * 9 + ks * 4 + lk) * 8];
                acc[q] = __builtin_amdgcn_mfma_f32_16x16x32_bf16(a, b, acc[q], 0, 0, 0);
            }
        }
        __syncthreads();
    }
    #pragma unroll
    for (int q = 0; q < 4; ++q) {
        int col = colbase + q * 16 + lr;
        float bb = bvec[col];
        #pragma unroll
        for (int r = 0; r < 4; ++r) {
            int row = rowbase + 16 * w + lk * 4 + r;
            z[(size_t)row * M_ + col] = tanh_f(acc[q][r] + bb);
        }
    }
}

__global__ __launch_bounds__(64) void fc2_softmax(
    const float* __restrict__ z, const float* __restrict__ wmat,
    const float* __restrict__ bvec, const int* __restrict__ perm,
    float* __restrict__ out)
{
    int bi = blockIdx.x;
    int lane = threadIdx.x;
    const float4* zr = (const float4*)(z + (size_t)bi * M_);
    const float4* w0 = (const float4*)(wmat);
    const float4* w1 = (const float4*)(wmat + M_);
    float s0 = 0.f, s1 = 0.f;
    for (int k = lane; k < M_ / 4; k += 64) {
        float4 zv = zr[k]; float4 a = w0[k]; float4 c = w1[k];
        s0 += zv.x * a.x + zv.y * a.y + zv.z * a.z + zv.w * a.w;
        s1 += zv.x * c.x + zv.y * c.y + zv.z * c.z + zv.w * c.w;
    }
    for (int off = 32; off; off >>= 1) {
        s0 += __shfl_down(s0, off);
        s1 += __shfl_down(s1, off);
    }
    if (lane == 0) {
        float l0 = s0 + bvec[0], l1 = s1 + bvec[1];
        float m = fmaxf(l0, l1);
        float lse = m + __logf(__expf(l0 - m) + __expf(l1 - m));
        int orig = perm[bi];
        out[orig * 2 + 0] = l0 - lse;
        out[orig * 2 + 1] = l1 - lse;
    }
}

// ---------------- launch ----------------

extern "C" void kernel_launch(void* const* d_in, const int* in_sizes, int n_in,
                              void* d_out, int out_size, void* d_ws, size_t ws_size,
                              hipStream_t stream)
{
    const int*   x       = (const int*)  d_in[0];
    const int*   x_index = (const int*)  d_in[1];
    const float* emb_t   = (const float*)d_in[2];
    const float* W_ih    = (const float*)d_in[3];
    const float* W_hh    = (const float*)d_in[4];
    const float* b_ih    = (const float*)d_in[5];
    const float* b_hh    = (const float*)d_in[6];
    const float* fc1_w   = (const float*)d_in[7];
    const float* fc1_b   = (const float*)d_in[8];
    const float* fc2_w   = (const float*)d_in[9];
    const float* fc2_b   = (const float*)d_in[10];
    const float* h0      = (const float*)d_in[11];
    const float* c0      = (const float*)d_in[12];
    float* out = (float*)d_out;

    char* p = (char*)d_ws;
    u16*   emb_bf = (u16*)p;   p += (size_t)B_ * T_ * E_ * 2;   // 134 MB
    u16*   wcat   = (u16*)p;   p += (size_t)G4H * KCAT * 2;     // 12.6 MB
    u16*   fc1wbf = (u16*)p;   p += (size_t)M_ * H_ * 2;        // 2 MB
    float* bias   = (float*)p; p += (size_t)G4H * 4;
    u16*   hbuf   = (u16*)p;   p += (size_t)2 * B_ * H_ * 2;    // ping-pong h
    float* c0p    = (float*)p; p += (size_t)B_ * H_ * 4;
    float* hn     = (float*)p; p += (size_t)B_ * H_ * 4;
    u16*   hnbf   = (u16*)p;   p += (size_t)B_ * H_ * 2;
    float* zbuf   = (float*)p; p += (size_t)B_ * M_ * 4;
    int*   perm   = (int*)p;   p += (size_t)B_ * 4;
    int*   sxi    = (int*)p;   p += (size_t)B_ * 4;
    u32*   flags  = (u32*)p;   p += (size_t)16 * 128 * 4;

    sort_rows <<<1,     256, 0, stream>>>(x_index, perm, sxi);
    prep_emb  <<<65536, 256, 0, stream>>>(x, emb_t, perm, emb_bf);
    prep_wcat <<<6144,  256, 0, stream>>>(W_hh, W_ih, wcat);
    prep_fc1w <<<1024,  256, 0, stream>>>(fc1_w, fc1wbf);
    prep_bias <<<16,    256, 0, stream>>>(b_ih, b_hh, bias);
    prep_state<<<1024,  256, 0, stream>>>(h0, c0, perm, hbuf, c0p);
    zero_flags<<<8,     256, 0, stream>>>(flags);

    lstm_persist<<<256, 512, 0, stream>>>(emb_bf, wcat, bias, c0p, sxi,
                                          hbuf, hn, flags);

    hn_convert <<<1024, 256, 0, stream>>>(hn, hnbf);
    fc1_kernel <<<dim3(16, 4), 256, 0, stream>>>(hnbf, fc1wbf, fc1_b, zbuf);
    fc2_softmax<<<256, 64, 0, stream>>>(zbuf, fc2_w, fc2_b, perm, out);
}

// Round 10
// 2958.486 us; speedup vs baseline: 2.9515x; 1.2221x over previous
//
#include <hip/hip_runtime.h>

typedef unsigned short u16;
typedef unsigned int u32;
typedef unsigned long long u64;
typedef __attribute__((ext_vector_type(8))) short short8;
typedef __attribute__((ext_vector_type(4))) float floatx4;
typedef __attribute__((ext_vector_type(4))) u32 u32x4;

#define B_   256
#define T_   512
#define E_   512
#define H_   1024
#define G4H  4096
#define KCAT 1536
#define M_   1024

// lstm_persist geometry
#define RG_N    8        // row groups
#define RG_ROWS 32       // rows per group
#define CB_N    32       // col blocks (32 h-cols each)
#define HC_B    32       // h-cols per block
#define NW      8        // waves per block
#define HSTRIDE 1032     // u16 per h-row in LDS (1024 + 8 pad; 2064B % 128 = 16)
#define ESTRIDE 520      // u16 per emb-row in LDS (512 + 8 pad; 1040B % 128 = 16)

__device__ __forceinline__ u16 f2bf(float f) {
    union { float f; unsigned u; } v; v.f = f;
    unsigned r = (v.u + 0x7fffu + ((v.u >> 16) & 1u)) >> 16;
    return (u16)r;
}
__device__ __forceinline__ float sigf(float x) {
    return __fdividef(1.0f, 1.0f + __expf(-x));
}
__device__ __forceinline__ float tanh_f(float x) {
    return 1.0f - __fdividef(2.0f, __expf(2.0f * x) + 1.0f);
}

// ---------------- prep kernels ----------------

// rank rows by x_index descending (stable): perm[rank]=orig, sxi[rank]=xi
__global__ void sort_rows(const int* __restrict__ x_index,
                          int* __restrict__ perm, int* __restrict__ sxi) {
    __shared__ int xl[B_];
    int tid = threadIdx.x;
    xl[tid] = x_index[tid];
    __syncthreads();
    int mine = xl[tid], rank = 0;
    for (int j = 0; j < B_; ++j)
        rank += (xl[j] > mine) || (xl[j] == mine && j < tid);
    perm[rank] = tid;
    sxi[rank] = mine;
}

// emb_bf[srow][t][e] = bf16(tab[x[perm[srow]][t]][e])
__global__ void prep_emb(const int* __restrict__ x, const float* __restrict__ tab,
                         const int* __restrict__ perm, u16* __restrict__ emb) {
    int idx = (blockIdx.x * 256 + threadIdx.x) * 4;   // [0, B*T*E)
    int srow = idx >> 18;                             // / (T*E)
    int t    = (idx >> 9) & 511;
    int e    = idx & 511;
    int orig = perm[srow];
    int xv   = x[orig * T_ + t];
    float4 v = *(const float4*)(tab + (size_t)xv * E_ + e);
    ushort4 o; o.x = f2bf(v.x); o.y = f2bf(v.y); o.z = f2bf(v.z); o.w = f2bf(v.w);
    *(ushort4*)(emb + idx) = o;
}

__global__ void prep_wcat(const float* __restrict__ Whh, const float* __restrict__ Wih,
                          u16* __restrict__ wcat) {
    int idx = (blockIdx.x * 256 + threadIdx.x) * 4;   // [0, 4096*1536)
    int g = idx / KCAT;
    int k = idx - g * KCAT;
    const float* src = (k < H_) ? (Whh + (size_t)g * H_ + k)
                                : (Wih + (size_t)g * E_ + (k - H_));
    float4 v = *(const float4*)src;
    ushort4 o; o.x = f2bf(v.x); o.y = f2bf(v.y); o.z = f2bf(v.z); o.w = f2bf(v.w);
    *(ushort4*)(wcat + idx) = o;
}

__global__ void prep_fc1w(const float* __restrict__ src, u16* __restrict__ dst) {
    int idx = (blockIdx.x * 256 + threadIdx.x) * 4;
    float4 v = *(const float4*)(src + idx);
    ushort4 o; o.x = f2bf(v.x); o.y = f2bf(v.y); o.z = f2bf(v.z); o.w = f2bf(v.w);
    *(ushort4*)(dst + idx) = o;
}

__global__ void prep_bias(const float* __restrict__ bih, const float* __restrict__ bhh,
                          float* __restrict__ bias) {
    int i = blockIdx.x * 256 + threadIdx.x;
    bias[i] = bih[i] + bhh[i];
}

// sorted h0 (bf16) and c0 (f32)
__global__ void prep_state(const float* __restrict__ h0, const float* __restrict__ c0,
                           const int* __restrict__ perm,
                           u16* __restrict__ hbuf0, float* __restrict__ c0p) {
    int i = blockIdx.x * 256 + threadIdx.x;           // [0, B*H)
    int srow = i >> 10, col = i & 1023;
    int orig = perm[srow];
    hbuf0[i] = f2bf(h0[(size_t)orig * H_ + col]);
    c0p[i]   = c0[(size_t)orig * H_ + col];
}

__global__ void zero_flags(u32* __restrict__ f) {
    f[blockIdx.x * 256 + threadIdx.x] = 0;
}

// ---------------- persistent LSTM (register-resident weights) ----------------
// 256 blocks x 512 threads (8 waves), 1 block/CU.
//   rg = bid>>5 owns sorted rows [rg*32, rg*32+32)
//   cb = bid&31 owns h-cols [cb*32, cb*32+32) (=128 gate-cols)
// Each wave holds 16 gate-cols x K=1536 of W in Breg (48 short8). A staged
// once per block into LDS, shared by 8 waves -> coherent h = 16 MB/step.
// Round-10 increments on the r9-verified base (all compiler-tracked, no asm):
//  * emb LDS double-buffer El[2]: the 16 emb-K MFMAs run from El[t&1] BEFORE
//    the poll; emb(t+1) is staged into El[(t+1)&1] after S1 (overlaps h-MFMAs).
//    Hazards: P4(t-1) writes El[t&1] -> S2(t-1) -> P1(t) reads. P1(t-1) reads
//    El[(t+1)&1] -> S1(t) -> P4(t) writes. Both barrier-separated.
//  * bias folded into accumulator init (acc00=acc10=biasv) - frees 8 VGPRs.
// Phases: P1 embMFMA -> P2 poll -> P3 stage h -> S1 -> P4 stage emb(t+1) ->
//         P5 hMFMA -> P6 epilogue+stores -> S2 (drains vmcnt) -> tid0 flag.

__global__ __launch_bounds__(512, 2) void lstm_persist(
    const u16* __restrict__ emb, const u16* __restrict__ wcat,
    const float* __restrict__ bias, const float* __restrict__ c0p,
    const int* __restrict__ sxi,
    u16* __restrict__ hbuf, float* __restrict__ hn, u32* __restrict__ flags)
{
    __shared__ __align__(16) u16 Hl[32 * HSTRIDE];        // 66,048 B (h, K 0..1023)
    __shared__ __align__(16) u16 El[2 * 32 * ESTRIDE];    // 66,560 B (emb dbuf, K 1024..1535)
    __shared__ __align__(16) float Gf_all[NW][640];       // 20,480 B

    const int tid  = threadIdx.x;
    const int w    = tid >> 6;
    const int lane = tid & 63;
    const int lr   = lane & 15;
    const int lk   = lane >> 4;
    const int rg   = blockIdx.x >> 5;
    const int cb   = blockIdx.x & 31;

    // ---- B fragments -> registers: wave w covers h-cols w*4..w*4+3 ----
    // output col n=lr maps to (gate = lr&3, hl = lr>>2); B[n][k] = W[gc(n)][k]
    const int gc = (lr & 3) * H_ + cb * HC_B + w * 4 + (lr >> 2);
    const u16* wrow = wcat + (size_t)gc * KCAT + lk * 8;
    short8 Breg[48];
    #pragma unroll
    for (int ks = 0; ks < 48; ++ks)
        Breg[ks] = *(const short8*)(wrow + ks * 32);

    const float biasv = bias[gc];   // bias for this lane's gate-col, folded into acc

    // ---- per-lane output state: lane = r0*2 + hp ----
    const int r0    = lane >> 1;                    // 0..31
    const int hp    = lane & 1;                     // 0..1
    const int hcol0 = cb * HC_B + w * 4 + hp * 2;
    const int rowg  = rg * RG_ROWS + r0;
    const int tmax  = sxi[rg * RG_ROWS];            // group max (sorted desc)
    const int xi    = sxi[rowg];
    float2 cc = *(const float2*)(c0p + (size_t)rowg * H_ + hcol0);

    const u32* fp = flags + rg * CB_N;              // 32 cohort flags

    // staging geometry: wave w stages rows [w*4, w*4+4)
    const size_t hrow_u16 = (size_t)(rg * RG_ROWS + w * 4) * H_;
    const int    erow_l   = w * 4 + (lane >> 4);                   // local row
    const u16*   erow_p   = emb + (size_t)(rg * RG_ROWS + erow_l) * T_ * E_;
    const int    echunk   = (lane & 15) * 8;                       // u16 offset

    // ---- prologue: stage emb(0) into El[0] ----
    {
        const u16* esrc = erow_p + echunk;          // t = 0
        u32x4 etmp[4];
        #pragma unroll
        for (int i = 0; i < 4; ++i)
            etmp[i] = *(const u32x4*)(esrc + i * 128);
        #pragma unroll
        for (int i = 0; i < 4; ++i)
            *(u32x4*)&El[erow_l * ESTRIDE + echunk + i * 128] = etmp[i];
    }
    __syncthreads();

    for (int t = 0; t <= tmax; ++t) {
        const u16* hread  = hbuf + (size_t)(t & 1) * (B_ * H_);
        u16*       hwrite = hbuf + (size_t)((t + 1) & 1) * (B_ * H_);

        floatx4 acc00 = {biasv, biasv, biasv, biasv}, acc01 = {0,0,0,0};
        floatx4 acc10 = {biasv, biasv, biasv, biasv}, acc11 = {0,0,0,0};

        // ---- P1: emb MFMAs (K 1024..1535) from El[t&1], BEFORE the poll ----
        {
            const int eb = (t & 1) * (32 * ESTRIDE);
            #pragma unroll
            for (int ks2 = 0; ks2 < 16; ++ks2) {
                short8 a0 = *(const short8*)&El[eb + lr * ESTRIDE + ks2 * 32 + lk * 8];
                short8 a1 = *(const short8*)&El[eb + (16 + lr) * ESTRIDE + ks2 * 32 + lk * 8];
                if (ks2 & 1) {
                    acc01 = __builtin_amdgcn_mfma_f32_16x16x32_bf16(a0, Breg[32 + ks2], acc01, 0, 0, 0);
                    acc11 = __builtin_amdgcn_mfma_f32_16x16x32_bf16(a1, Breg[32 + ks2], acc11, 0, 0, 0);
                } else {
                    acc00 = __builtin_amdgcn_mfma_f32_16x16x32_bf16(a0, Breg[32 + ks2], acc00, 0, 0, 0);
                    acc10 = __builtin_amdgcn_mfma_f32_16x16x32_bf16(a1, Breg[32 + ks2], acc10, 0, 0, 0);
                }
            }
        }

        // ---- P2: wait for h_t (32 producer blocks of this row-group) ----
        if (t > 0) {
            while (true) {
                u32 v = (lane < 32)
                    ? __hip_atomic_load(fp + lane, __ATOMIC_RELAXED,
                                        __HIP_MEMORY_SCOPE_AGENT)
                    : (u32)t;
                if (__all((int)(v >= (u32)t))) break;
                __builtin_amdgcn_s_sleep(1);
            }
        }

        // ---- P3: stage h(t): 8KB/wave via coherent atomic u64 loads ----
        {
            u64* hsrc = (u64*)(hread + hrow_u16);
            #pragma unroll
            for (int b = 0; b < 2; ++b) {
                u64 htmp[8];
                #pragma unroll
                for (int i = 0; i < 8; ++i)
                    htmp[i] = __hip_atomic_load(hsrc + (b * 8 + i) * 64 + lane,
                                                __ATOMIC_RELAXED,
                                                __HIP_MEMORY_SCOPE_AGENT);
                #pragma unroll
                for (int i = 0; i < 8; ++i) {
                    int hb = (b * 8 + i) * 512 + lane * 8;   // byte in 8KB slab
                    *(u64*)&Hl[(w * 4 + (hb >> 11)) * HSTRIDE + ((hb & 2047) >> 1)] = htmp[i];
                }
            }
        }

        __syncthreads();   // S1: h fully staged (block-wide)

        // ---- P4: stage emb(t+1) into El[(t+1)&1] (overlaps P5) ----
        if (t < tmax) {
            const u16* esrc = erow_p + (size_t)(t + 1) * E_ + echunk;
            u32x4 etmp[4];
            #pragma unroll
            for (int i = 0; i < 4; ++i)
                etmp[i] = *(const u32x4*)(esrc + i * 128);
            const int eb2 = ((t + 1) & 1) * (32 * ESTRIDE);
            #pragma unroll
            for (int i = 0; i < 4; ++i)
                *(u32x4*)&El[eb2 + erow_l * ESTRIDE + echunk + i * 128] = etmp[i];
        }

        // ---- P5: h MFMAs (K 0..1023) from Hl ----
        #pragma unroll
        for (int ks = 0; ks < 32; ++ks) {
            short8 a0 = *(const short8*)&Hl[lr * HSTRIDE + ks * 32 + lk * 8];
            short8 a1 = *(const short8*)&Hl[(16 + lr) * HSTRIDE + ks * 32 + lk * 8];
            if (ks & 1) {
                acc01 = __builtin_amdgcn_mfma_f32_16x16x32_bf16(a0, Breg[ks], acc01, 0, 0, 0);
                acc11 = __builtin_amdgcn_mfma_f32_16x16x32_bf16(a1, Breg[ks], acc11, 0, 0, 0);
            } else {
                acc00 = __builtin_amdgcn_mfma_f32_16x16x32_bf16(a0, Breg[ks], acc00, 0, 0, 0);
                acc10 = __builtin_amdgcn_mfma_f32_16x16x32_bf16(a1, Breg[ks], acc10, 0, 0, 0);
            }
        }

        // ---- P6: epilogue: wave-private LDS transpose (Gf[32 rows][20]) ----
        float* Gf = Gf_all[w];
        #pragma unroll
        for (int r = 0; r < 4; ++r) {
            Gf[(lk * 4 + r) * 20 + lr]      = acc00[r] + acc01[r];
            Gf[(16 + lk * 4 + r) * 20 + lr] = acc10[r] + acc11[r];
        }
        float4 gA = *(float4*)&Gf[r0 * 20 + hp * 8];        // col hcol0:   i,f,g,o (bias included)
        float4 gB = *(float4*)&Gf[r0 * 20 + hp * 8 + 4];    // col hcol0+1: i,f,g,o

        float i0 = sigf(gA.x), f0 = sigf(gA.y);
        float q0 = tanh_f(gA.z), o0 = sigf(gA.w);
        float i1 = sigf(gB.x), f1 = sigf(gB.y);
        float q1 = tanh_f(gB.z), o1 = sigf(gB.w);
        cc.x = f0 * cc.x + i0 * q0;
        cc.y = f1 * cc.y + i1 * q1;
        float h0f = o0 * tanh_f(cc.x);
        float h1f = o1 * tanh_f(cc.y);

        u32 packed = (u32)f2bf(h0f) | ((u32)f2bf(h1f) << 16);
        __hip_atomic_store((u32*)(hwrite + (size_t)rowg * H_ + hcol0), packed,
                           __ATOMIC_RELAXED, __HIP_MEMORY_SCOPE_AGENT);
        if (xi == t)
            *(float2*)(hn + (size_t)rowg * H_ + hcol0) = make_float2(h0f, h1f);

        // S2: __syncthreads — compiler drains vmcnt(0) before s_barrier, so all
        // waves' coherent h stores are at the MALL before tid0 raises the flag.
        __syncthreads();
        if (tid == 0)
            __hip_atomic_store(flags + rg * CB_N + cb, (u32)(t + 1),
                               __ATOMIC_RELAXED, __HIP_MEMORY_SCOPE_AGENT);
    }
}

// ---------------- tail ----------------

__global__ void hn_convert(const float* __restrict__ hn, u16* __restrict__ hnbf) {
    int i = blockIdx.x * 256 + threadIdx.x;
    hnbf[i] = f2bf(hn[i]);
}

__global__ __launch_bounds__(256) void fc1_kernel(
    const u16* __restrict__ A, const u16* __restrict__ Bw,
    const float* __restrict__ bvec, float* __restrict__ z)
{
    __shared__ __align__(16) u16 Als[64 * 72];
    __shared__ __align__(16) u16 Bls[64 * 72];
    const int tid = threadIdx.x;
    const int rowbase = blockIdx.y * 64;
    const int colbase = blockIdx.x * 64;
    floatx4 acc[4] = {{0,0,0,0},{0,0,0,0},{0,0,0,0},{0,0,0,0}};
    const int w = tid >> 6, lane = tid & 63, lr = lane & 15, lk = lane >> 4;

    for (int s = 0; s < H_ / 64; ++s) {
        int k0 = s * 64;
        #pragma unroll
        for (int cc2 = 0; cc2 < 2; ++cc2) {
            int c = tid + cc2 * 256;
            int row = c >> 3, kg = c & 7, kglob = k0 + kg * 8;
            *(u32x4*)&Als[(row * 9 + kg) * 8] =
                *(const u32x4*)(A + (size_t)(rowbase + row) * H_ + kglob);
            *(u32x4*)&Bls[(row * 9 + kg) * 8] =
                *(const u32x4*)(Bw + (size_t)(colbase + row) * H_ + kglob);
        }
        __syncthreads();
        #pragma unroll
        for (int ks = 0; ks < 2; ++ks) {
            short8 a = *(const short8*)&Als[((16 * w + lr) * 9 + ks * 4 + lk) * 8];
            #pragma unroll
            for (int q = 0; q < 4; ++q) {
                short8 b = *(const short8*)&Bls[((q * 16 + lr) * 9 + ks * 4 + lk) * 8];
                acc[q] = __builtin_amdgcn_mfma_f32_16x16x32_bf16(a, b, acc[q], 0, 0, 0);
            }
        }
        __syncthreads();
    }
    #pragma unroll
    for (int q = 0; q < 4; ++q) {
        int col = colbase + q * 16 + lr;
        float bb = bvec[col];
        #pragma unroll
        for (int r = 0; r < 4; ++r) {
            int row = rowbase + 16 * w + lk * 4 + r;
            z[(size_t)row * M_ + col] = tanh_f(acc[q][r] + bb);
        }
    }
}

__global__ __launch_bounds__(64) void fc2_softmax(
    const float* __restrict__ z, const float* __restrict__ wmat,
    const float* __restrict__ bvec, const int* __restrict__ perm,
    float* __restrict__ out)
{
    int bi = blockIdx.x;
    int lane = threadIdx.x;
    const float4* zr = (const float4*)(z + (size_t)bi * M_);
    const float4* w0 = (const float4*)(wmat);
    const float4* w1 = (const float4*)(wmat + M_);
    float s0 = 0.f, s1 = 0.f;
    for (int k = lane; k < M_ / 4; k += 64) {
        float4 zv = zr[k]; float4 a = w0[k]; float4 c = w1[k];
        s0 += zv.x * a.x + zv.y * a.y + zv.z * a.z + zv.w * a.w;
        s1 += zv.x * c.x + zv.y * c.y + zv.z * c.z + zv.w * c.w;
    }
    for (int off = 32; off; off >>= 1) {
        s0 += __shfl_down(s0, off);
        s1 += __shfl_down(s1, off);
    }
    if (lane == 0) {
        float l0 = s0 + bvec[0], l1 = s1 + bvec[1];
        float m = fmaxf(l0, l1);
        float lse = m + __logf(__expf(l0 - m) + __expf(l1 - m));
        int orig = perm[bi];
        out[orig * 2 + 0] = l0 - lse;
        out[orig * 2 + 1] = l1 - lse;
    }
}

// ---------------- launch ----------------

extern "C" void kernel_launch(void* const* d_in, const int* in_sizes, int n_in,
                              void* d_out, int out_size, void* d_ws, size_t ws_size,
                              hipStream_t stream)
{
    const int*   x       = (const int*)  d_in[0];
    const int*   x_index = (const int*)  d_in[1];
    const float* emb_t   = (const float*)d_in[2];
    const float* W_ih    = (const float*)d_in[3];
    const float* W_hh    = (const float*)d_in[4];
    const float* b_ih    = (const float*)d_in[5];
    const float* b_hh    = (const float*)d_in[6];
    const float* fc1_w   = (const float*)d_in[7];
    const float* fc1_b   = (const float*)d_in[8];
    const float* fc2_w   = (const float*)d_in[9];
    const float* fc2_b   = (const float*)d_in[10];
    const float* h0      = (const float*)d_in[11];
    const float* c0      = (const float*)d_in[12];
    float* out = (float*)d_out;

    char* p = (char*)d_ws;
    u16*   emb_bf = (u16*)p;   p += (size_t)B_ * T_ * E_ * 2;   // 134 MB
    u16*   wcat   = (u16*)p;   p += (size_t)G4H * KCAT * 2;     // 12.6 MB
    u16*   fc1wbf = (u16*)p;   p += (size_t)M_ * H_ * 2;        // 2 MB
    float* bias   = (float*)p; p += (size_t)G4H * 4;
    u16*   hbuf   = (u16*)p;   p += (size_t)2 * B_ * H_ * 2;    // ping-pong h
    float* c0p    = (float*)p; p += (size_t)B_ * H_ * 4;
    float* hn     = (float*)p; p += (size_t)B_ * H_ * 4;
    u16*   hnbf   = (u16*)p;   p += (size_t)B_ * H_ * 2;
    float* zbuf   = (float*)p; p += (size_t)B_ * M_ * 4;
    int*   perm   = (int*)p;   p += (size_t)B_ * 4;
    int*   sxi    = (int*)p;   p += (size_t)B_ * 4;
    u32*   flags  = (u32*)p;   p += (size_t)16 * 128 * 4;

    sort_rows <<<1,     256, 0, stream>>>(x_index, perm, sxi);
    prep_emb  <<<65536, 256, 0, stream>>>(x, emb_t, perm, emb_bf);
    prep_wcat <<<6144,  256, 0, stream>>>(W_hh, W_ih, wcat);
    prep_fc1w <<<1024,  256, 0, stream>>>(fc1_w, fc1wbf);
    prep_bias <<<16,    256, 0, stream>>>(b_ih, b_hh, bias);
    prep_state<<<1024,  256, 0, stream>>>(h0, c0, perm, hbuf, c0p);
    zero_flags<<<8,     256, 0, stream>>>(flags);

    lstm_persist<<<256, 512, 0, stream>>>(emb_bf, wcat, bias, c0p, sxi,
                                          hbuf, hn, flags);

    hn_convert <<<1024, 256, 0, stream>>>(hn, hnbf);
    fc1_kernel <<<dim3(16, 4), 256, 0, stream>>>(hnbf, fc1wbf, fc1_b, zbuf);
    fc2_softmax<<<256, 64, 0, stream>>>(zbuf, fc2_w, fc2_b, perm, out);
}